// Round 9
// baseline (456.278 us; speedup 1.0000x reference)
//
#include <hip/hip_runtime.h>
#include <cstdint>
#include <cstddef>

typedef __bf16 bf16;
typedef __bf16 bf16x8 __attribute__((ext_vector_type(8)));
typedef float  f32x4  __attribute__((ext_vector_type(4)));

#define MFMA(A, B, C) __builtin_amdgcn_mfma_f32_16x16x32_bf16(A, B, C, 0, 0, 0)

__device__ __forceinline__ void gload_lds16(const void* g, void* l) {
  __builtin_amdgcn_global_load_lds((const __attribute__((address_space(1))) void*)g,
                                   (__attribute__((address_space(3))) void*)l, 16, 0, 0);
}

// ---------------- convert x (fp32 -> bf16), 8 elems/thread ----------------
__global__ __launch_bounds__(256) void k_cvt_x(const float* __restrict__ x,
                                               bf16* __restrict__ xb) {
  int i = blockIdx.x * 256 + threadIdx.x;  // 2,097,152 threads exactly
  const float4* p = (const float4*)x;
  float4 a = p[i * 2 + 0], b = p[i * 2 + 1];
  bf16x8 o;
  o[0] = (bf16)a.x; o[1] = (bf16)a.y; o[2] = (bf16)a.z; o[3] = (bf16)a.w;
  o[4] = (bf16)b.x; o[5] = (bf16)b.y; o[6] = (bf16)b.z; o[7] = (bf16)b.w;
  ((bf16x8*)xb)[i] = o;
}

// ------- convert + transpose W: wt[j][k] = W_sel[k][j&1023], j in [0,3072) -------
__global__ __launch_bounds__(256) void k_cvt_w(const float* __restrict__ Wq,
                                               const float* __restrict__ Wk,
                                               const float* __restrict__ Wv,
                                               bf16* __restrict__ wt) {
  int t = blockIdx.x * 256 + threadIdx.x;  // 393,216 exactly
  int j = t >> 7;
  int ko = (t & 127) << 3;
  const float* W = (j < 1024) ? Wq : (j < 2048) ? Wk : Wv;
  int jl = j & 1023;
  bf16x8 o;
#pragma unroll
  for (int e = 0; e < 8; ++e) o[e] = (bf16)W[(size_t)(ko + e) * 1024 + jl];
  *(bf16x8*)(wt + (size_t)j * 1024 + ko) = o;
}

// ---------------- fused QKV GEMM: C[16384][3072] = xb @ wt^T ----------------
__global__ __launch_bounds__(256, 2)
void k_qkv(const bf16* __restrict__ xb, const bf16* __restrict__ wt,
           const float* __restrict__ bq, const float* __restrict__ bk,
           const float* __restrict__ bv,
           bf16* __restrict__ q, bf16* __restrict__ k, bf16* __restrict__ v) {
  __shared__ bf16 As[128 * 64];
  __shared__ bf16 Bs[128 * 64];
  const int tid = threadIdx.x, lane = tid & 63, w = tid >> 6;
  const int wm = w >> 1, wn = w & 1;
  const int bm = blockIdx.x, bn = blockIdx.y;

  f32x4 acc[16];
#pragma unroll
  for (int i = 0; i < 16; ++i) acc[i] = f32x4{0.f, 0.f, 0.f, 0.f};

  for (int kt = 0; kt < 16; ++kt) {
    __syncthreads();
#pragma unroll
    for (int i = 0; i < 4; ++i) {
      int chunk = (w * 4 + i) * 64 + lane;
      int row = chunk >> 3, ch = chunk & 7;
      size_t gofs = ((size_t)row * 1024 + (size_t)kt * 64) * 2 + (size_t)((ch ^ (row & 7)) << 4);
      gload_lds16((const char*)(xb + (size_t)bm * 128 * 1024) + gofs,
                  (char*)As + (w * 4 + i) * 1024);
      gload_lds16((const char*)(wt + (size_t)bn * 128 * 1024) + gofs,
                  (char*)Bs + (w * 4 + i) * 1024);
    }
    __syncthreads();
#pragma unroll
    for (int s = 0; s < 2; ++s) {
      bf16x8 af[4], bf_[4];
#pragma unroll
      for (int mi = 0; mi < 4; ++mi) {
        int row = wm * 64 + mi * 16 + (lane & 15);
        af[mi] = *(const bf16x8*)((const char*)As +
                  ((row * 128 + s * 64 + (lane >> 4) * 16) ^ ((row & 7) << 4)));
      }
#pragma unroll
      for (int ni = 0; ni < 4; ++ni) {
        int row = wn * 64 + ni * 16 + (lane & 15);
        bf_[ni] = *(const bf16x8*)((const char*)Bs +
                  ((row * 128 + s * 64 + (lane >> 4) * 16) ^ ((row & 7) << 4)));
      }
#pragma unroll
      for (int mi = 0; mi < 4; ++mi)
#pragma unroll
        for (int ni = 0; ni < 4; ++ni)
          acc[mi * 4 + ni] = MFMA(af[mi], bf_[ni], acc[mi * 4 + ni]);
    }
  }
  const int jsel = bn >> 3;  // 0:Q 1:K 2:V
  const float* bias = jsel == 0 ? bq : jsel == 1 ? bk : bv;
  bf16* outp = jsel == 0 ? q : jsel == 1 ? k : v;
  const float scale = jsel == 0 ? 0.03125f : 1.0f;
#pragma unroll
  for (int ni = 0; ni < 4; ++ni) {
    int col = bn * 128 + wn * 64 + ni * 16 + (lane & 15);
    int jl = col & 1023;
    float bsv = bias[jl];
#pragma unroll
    for (int mi = 0; mi < 4; ++mi) {
#pragma unroll
      for (int e = 0; e < 4; ++e) {
        int tok = bm * 128 + wm * 64 + mi * 16 + (lane >> 4) * 4 + e;
        outp[(size_t)tok * 1024 + jl] = (bf16)((acc[mi * 4 + ni][e] + bsv) * scale);
      }
    }
  }
}

// ---------------- V transpose: vt[b][d][n] = v[b][n][d] ----------------
__global__ __launch_bounds__(256)
void k_trv(const bf16* __restrict__ v, bf16* __restrict__ vt) {
  __shared__ bf16 tl[64][80];
  const int n0 = blockIdx.x * 64, d0 = blockIdx.y * 64, b = blockIdx.z;
  const int tid = threadIdx.x;
#pragma unroll
  for (int it = 0; it < 2; ++it) {
    int task = tid + it * 256;
    int row = task >> 3, oct = task & 7;
    *(bf16x8*)&tl[row][oct * 8] =
        *(const bf16x8*)(v + ((size_t)(b * 2048 + n0 + row) * 1024 + d0 + oct * 8));
  }
  __syncthreads();
#pragma unroll
  for (int it = 0; it < 2; ++it) {
    int task = tid + it * 256;
    int dr = task >> 3, noct = task & 7;
    bf16x8 o;
#pragma unroll
    for (int e = 0; e < 8; ++e) o[e] = tl[noct * 8 + e][dr];
    *(bf16x8*)(vt + ((size_t)(b * 1024 + d0 + dr) * 2048 + n0 + noct * 8)) = o;
  }
}

// ---------------- S = Q @ K^T (per batch), bf16 out to d_out ----------------
__global__ __launch_bounds__(256, 2)
void k_qk(const bf16* __restrict__ q, const bf16* __restrict__ k,
          bf16* __restrict__ S) {
  __shared__ bf16 As[128 * 64];
  __shared__ bf16 Bs[128 * 64];
  const int tid = threadIdx.x, lane = tid & 63, w = tid >> 6;
  const int wm = w >> 1, wn = w & 1;
  const int bm = blockIdx.x, bn = blockIdx.y, b = blockIdx.z;
  const bf16* Ab = q + (size_t)(b * 2048 + bm * 128) * 1024;
  const bf16* Bb = k + (size_t)(b * 2048 + bn * 128) * 1024;

  f32x4 acc[16];
#pragma unroll
  for (int i = 0; i < 16; ++i) acc[i] = f32x4{0.f, 0.f, 0.f, 0.f};

  for (int kt = 0; kt < 16; ++kt) {
    __syncthreads();
#pragma unroll
    for (int i = 0; i < 4; ++i) {
      int chunk = (w * 4 + i) * 64 + lane;
      int row = chunk >> 3, ch = chunk & 7;
      size_t gofs = ((size_t)row * 1024 + (size_t)kt * 64) * 2 + (size_t)((ch ^ (row & 7)) << 4);
      gload_lds16((const char*)Ab + gofs, (char*)As + (w * 4 + i) * 1024);
      gload_lds16((const char*)Bb + gofs, (char*)Bs + (w * 4 + i) * 1024);
    }
    __syncthreads();
#pragma unroll
    for (int s = 0; s < 2; ++s) {
      bf16x8 af[4], bf_[4];
#pragma unroll
      for (int mi = 0; mi < 4; ++mi) {
        int row = wm * 64 + mi * 16 + (lane & 15);
        af[mi] = *(const bf16x8*)((const char*)As +
                  ((row * 128 + s * 64 + (lane >> 4) * 16) ^ ((row & 7) << 4)));
      }
#pragma unroll
      for (int ni = 0; ni < 4; ++ni) {
        int row = wn * 64 + ni * 16 + (lane & 15);
        bf_[ni] = *(const bf16x8*)((const char*)Bs +
                  ((row * 128 + s * 64 + (lane >> 4) * 16) ^ ((row & 7) << 4)));
      }
#pragma unroll
      for (int mi = 0; mi < 4; ++mi)
#pragma unroll
        for (int ni = 0; ni < 4; ++ni)
          acc[mi * 4 + ni] = MFMA(af[mi], bf_[ni], acc[mi * 4 + ni]);
    }
  }
#pragma unroll
  for (int ni = 0; ni < 4; ++ni) {
    int col = bn * 128 + wn * 64 + ni * 16 + (lane & 15);
#pragma unroll
    for (int mi = 0; mi < 4; ++mi) {
#pragma unroll
      for (int e = 0; e < 4; ++e) {
        int qr = bm * 128 + wm * 64 + mi * 16 + (lane >> 4) * 4 + e;
        S[(size_t)(b * 2048 + qr) * 2048 + col] = (bf16)acc[mi * 4 + ni][e];
      }
    }
  }
}

// ---------------- row softmax: P[row] = softmax(mask(S[row])) ----------------
// One 64-lane wave per row (4 rows per 256-thread block, 4096 blocks).
// No barriers, no LDS reductions. Masked entries -> -1e30 (exp underflows to
// 0; fully-masked rows degrade to uniform, matching reference semantics).
__global__ __launch_bounds__(256)
void k_sm(const bf16* __restrict__ S, const int* __restrict__ mask,
          bf16* __restrict__ P) {
  const int row = blockIdx.x * 4 + (threadIdx.x >> 6);
  const int l = threadIdx.x & 63;
  const int b = row >> 11;
  const bf16* Sr = S + (size_t)row * 2048;
  const int* mrow = mask + b * 2048;
  float s[32];
  float mx = -1e30f;
#pragma unroll
  for (int j = 0; j < 4; ++j) {
    bf16x8 sv = *(const bf16x8*)(Sr + (j * 64 + l) * 8);
    int4 m0 = *(const int4*)(mrow + (j * 64 + l) * 8);
    int4 m1 = *(const int4*)(mrow + (j * 64 + l) * 8 + 4);
    int mm[8] = {m0.x, m0.y, m0.z, m0.w, m1.x, m1.y, m1.z, m1.w};
#pragma unroll
    for (int e = 0; e < 8; ++e) {
      s[j * 8 + e] = mm[e] ? (float)sv[e] : -1e30f;
      mx = fmaxf(mx, s[j * 8 + e]);
    }
  }
#pragma unroll
  for (int off = 1; off < 64; off <<= 1) mx = fmaxf(mx, __shfl_xor(mx, off));
  float sum = 0.f;
#pragma unroll
  for (int i = 0; i < 32; ++i) { s[i] = __expf(s[i] - mx); sum += s[i]; }
#pragma unroll
  for (int off = 1; off < 64; off <<= 1) sum += __shfl_xor(sum, off);
  float inv = sum > 0.f ? 1.f / sum : 0.f;
#pragma unroll
  for (int j = 0; j < 4; ++j) {
    bf16x8 pv;
#pragma unroll
    for (int e = 0; e < 8; ++e) pv[e] = (bf16)(s[j * 8 + e] * inv);
    *(bf16x8*)(P + (size_t)row * 2048 + (j * 64 + l) * 8) = pv;
  }
}

// ---------------- O = P @ V (per batch), fp32 out ----------------
__global__ __launch_bounds__(256, 2)
void k_pv(const bf16* __restrict__ P, const bf16* __restrict__ vt,
          float* __restrict__ O) {
  __shared__ bf16 As[128 * 64];
  __shared__ bf16 Bs[128 * 64];
  const int tid = threadIdx.x, lane = tid & 63, w = tid >> 6;
  const int wm = w >> 1, wn = w & 1;
  const int bm = blockIdx.x, bn = blockIdx.y, b = blockIdx.z;
  const bf16* Ab = P + (size_t)(b * 2048 + bm * 128) * 2048;
  const bf16* Bb = vt + (size_t)(b * 1024 + bn * 128) * 2048;

  f32x4 acc[16];
#pragma unroll
  for (int i = 0; i < 16; ++i) acc[i] = f32x4{0.f, 0.f, 0.f, 0.f};

  for (int kt = 0; kt < 32; ++kt) {
    __syncthreads();
#pragma unroll
    for (int i = 0; i < 4; ++i) {
      int chunk = (w * 4 + i) * 64 + lane;
      int row = chunk >> 3, ch = chunk & 7;
      size_t gofs = ((size_t)row * 2048 + (size_t)kt * 64) * 2 + (size_t)((ch ^ (row & 7)) << 4);
      gload_lds16((const char*)Ab + gofs, (char*)As + (w * 4 + i) * 1024);
      gload_lds16((const char*)Bb + gofs, (char*)Bs + (w * 4 + i) * 1024);
    }
    __syncthreads();
#pragma unroll
    for (int s = 0; s < 2; ++s) {
      bf16x8 af[4], bf_[4];
#pragma unroll
      for (int mi = 0; mi < 4; ++mi) {
        int row = wm * 64 + mi * 16 + (lane & 15);
        af[mi] = *(const bf16x8*)((const char*)As +
                  ((row * 128 + s * 64 + (lane >> 4) * 16) ^ ((row & 7) << 4)));
      }
#pragma unroll
      for (int ni = 0; ni < 4; ++ni) {
        int row = wn * 64 + ni * 16 + (lane & 15);
        bf_[ni] = *(const bf16x8*)((const char*)Bs +
                  ((row * 128 + s * 64 + (lane >> 4) * 16) ^ ((row & 7) << 4)));
      }
#pragma unroll
      for (int mi = 0; mi < 4; ++mi)
#pragma unroll
        for (int ni = 0; ni < 4; ++ni)
          acc[mi * 4 + ni] = MFMA(af[mi], bf_[ni], acc[mi * 4 + ni]);
    }
  }
#pragma unroll
  for (int ni = 0; ni < 4; ++ni) {
    int col = bn * 128 + wn * 64 + ni * 16 + (lane & 15);
#pragma unroll
    for (int mi = 0; mi < 4; ++mi) {
#pragma unroll
      for (int e = 0; e < 4; ++e) {
        int qr = bm * 128 + wm * 64 + mi * 16 + (lane >> 4) * 4 + e;
        O[(size_t)(b * 2048 + qr) * 1024 + col] = acc[mi * 4 + ni][e];
      }
    }
  }
}

extern "C" void kernel_launch(void* const* d_in, const int* in_sizes, int n_in,
                              void* d_out, int out_size, void* d_ws, size_t ws_size,
                              hipStream_t stream) {
  const float* x  = (const float*)d_in[0];
  const int* mask = (const int*)d_in[1];
  const float* Wq = (const float*)d_in[2];
  const float* bq = (const float*)d_in[3];
  const float* Wk = (const float*)d_in[4];
  const float* bk = (const float*)d_in[5];
  const float* Wv = (const float*)d_in[6];
  const float* bv = (const float*)d_in[7];
  float* out = (float*)d_out;

  char* ws = (char*)d_ws;
  // ws layout (bytes): xb 0..32M | wt 32M..38.3M | q 38.3M..71.9M | k 71.9M..105.4M | v 105.4M..139M
  bf16* xb = (bf16*)(ws);
  bf16* wt = (bf16*)(ws + 33554432);
  bf16* q  = (bf16*)(ws + 39845888);
  bf16* k  = (bf16*)(ws + 73400320);
  bf16* v  = (bf16*)(ws + 106954752);
  bf16* vt = xb;                    // xb dead after k_qkv (32MB, exact fit)
  bf16* S  = (bf16*)d_out;          // 16384x2048 bf16 = 64MB = out buffer exactly
  bf16* P  = q;                     // q+k slots (64MB contiguous), dead after k_qk

  k_cvt_x<<<8192, 256, 0, stream>>>(x, xb);
  k_cvt_w<<<1536, 256, 0, stream>>>(Wq, Wk, Wv, wt);
  k_qkv<<<dim3(128, 24), 256, 0, stream>>>(xb, wt, bq, bk, bv, q, k, v);
  k_trv<<<dim3(32, 16, 8), 256, 0, stream>>>(v, vt);
  k_qk<<<dim3(16, 16, 8), 256, 0, stream>>>(q, k, S);
  k_sm<<<4096, 256, 0, stream>>>(S, mask, P);
  k_pv<<<dim3(16, 8, 8), 256, 0, stream>>>(P, vt, out);
}